// Round 9
// baseline (202.082 us; speedup 1.0000x reference)
//
#include <hip/hip_runtime.h>
#include <hip/hip_fp16.h>

#define N_NODES 50000
#define N_EDGES 800000
#define N_GRAPHS 64
#define N_PAD 50048

#define CB 256                              // lsort blocks (= edge chunks)
#define EPB (N_EDGES / CB)                  // 3125 edges per block (exact)
#define NBUCKET ((N_NODES + 255) / 256)     // 196 coarse buckets (dst>>8)

typedef _Float16 f16x8 __attribute__((ext_vector_type(8)));
typedef float f32x4 __attribute__((ext_vector_type(4)));

// fp8 e4m3 <-> f16 via bit-splice: byte b at f16 bits [14:7] represents value*2^-8
// (exact for normals and subnormals). The 2^8/32 net scale is folded into Wt2.
__device__ __forceinline__ unsigned splice2(unsigned z) {
    return ((z & 0x80u) << 8) | ((z & 0x7fu) << 7) |
           ((z & 0x8000u) << 16) | ((z & 0x7f00u) << 15);
}
__device__ __forceinline__ f16x8 dec8(uint2 w) {
    union { unsigned u[4]; f16x8 v; } o;
    o.u[0] = splice2(w.x);
    o.u[1] = splice2(w.x >> 16);
    o.u[2] = splice2(w.y);
    o.u[3] = splice2(w.y >> 16);
    return o.v;
}

// ---------------- prep: Wt2*8 ->fp16, Wcz = [W_in;b_in]@W1 fp32, pcnt, zeros --------

__global__ void k_prep(const float* __restrict__ W_in, const float* __restrict__ b_in,
                       const float* __restrict__ W1, const float* __restrict__ W2,
                       _Float16* __restrict__ Wt2, float* __restrict__ Wcz,
                       float* psum, float* pmax, int* totals,
                       const int* __restrict__ batch, float* __restrict__ pcnt) {
    int idx = blockIdx.x * blockDim.x + threadIdx.x;
    if (idx < 128 * 128) {                   // Wt2[n*128+k] = 8 * W2[k*128+n]
        int n = idx >> 7, k = idx & 127;     // (x8 compensates fp8 stored value = G/8)
        Wt2[idx] = (_Float16)(W2[k * 128 + n] * 8.0f);
    } else if (idx < 128 * 128 + 1024) {     // Wcz[k*128+ch], k<6: W_in@W1, k=6: b_in@W1
        int j = idx - 128 * 128;
        int ch = j >> 3, k = j & 7;
        float acc = 0.f;
        if (k < 6) {
            for (int q = 0; q < 64; q++) acc += W_in[k * 64 + q] * W1[q * 128 + ch];
        } else if (k == 6) {
            for (int q = 0; q < 64; q++) acc += b_in[q] * W1[q * 128 + ch];
        }
        Wcz[k * 128 + ch] = acc;
    }
    if (idx < N_GRAPHS * 128) { psum[idx] = 0.f; pmax[idx] = 0.f; }
    if (idx < 256) totals[idx] = 0;
    // pcnt via lower_bound on sorted batch (block 0 only)
    if (blockIdx.x == 0) {
        __shared__ int shp[N_GRAPHS + 1];
        int tt = threadIdx.x;
        if (tt <= N_GRAPHS) {
            int lo = 0, hi = N_NODES;
            while (lo < hi) {
                int mid = (lo + hi) >> 1;
                if (batch[mid] < tt) lo = mid + 1; else hi = mid;
            }
            shp[tt] = lo;
        }
        __syncthreads();
        if (tt < N_GRAPHS) pcnt[tt] = (float)(shp[tt + 1] - shp[tt]);
    }
}

// ---------------- CSR build: LDS-local bucket sort, coalesced segment writes --------
// One histogram per chunk (not two), LDS scatter into stage, coalesced esort write.
// lstart[i*256+b] = within-chunk start of bucket i in block b's segment (i in 0..196).
__global__ __launch_bounds__(256) void k_lsort(
        const int* __restrict__ src, const int* __restrict__ dst,
        int* __restrict__ totals, unsigned int* __restrict__ esort,
        int* __restrict__ lstart) {
    __shared__ int hist[256];
    __shared__ int sc[256];
    __shared__ int cur[256];
    __shared__ unsigned stage[EPB];          // 12.5 KB
    int t = threadIdx.x, b = blockIdx.x;
    hist[t] = 0;
    __syncthreads();
    int e0 = b * EPB;
    for (int e = e0 + t; e < e0 + EPB; e += 256)
        atomicAdd(&hist[dst[e] >> 8], 1);
    __syncthreads();
    int v = hist[t];
    sc[t] = v;
    __syncthreads();
    for (int off = 1; off < 256; off <<= 1) {
        int u = (t >= off) ? sc[t - off] : 0;
        __syncthreads();
        sc[t] += u;
        __syncthreads();
    }
    int base = sc[t] - v;                    // exclusive scan within chunk
    cur[t] = base;
    if (t < NBUCKET) {
        lstart[t * 256 + b] = base;
        if (v > 0) atomicAdd(&totals[t], v);
    }
    if (t == 0) lstart[NBUCKET * 256 + b] = EPB;
    __syncthreads();
    for (int e = e0 + t; e < e0 + EPB; e += 256) {
        int d = dst[e];
        int slot = atomicAdd(&cur[d >> 8], 1);
        stage[slot] = ((unsigned)(d & 255) << 16) | (unsigned)src[e];  // src < 2^16
    }
    __syncthreads();
    for (int i = t; i < EPB; i += 256)       // coalesced segment write-out
        esort[e0 + i] = stage[i];
}

// one block per bucket: reconstruct bucket from 256 chunk-segments; fine hist ->
// row_ptr/dinv/pfeat; cursor fill of col. Element -> segment via LDS binary search.
__global__ __launch_bounds__(256) void k_fine_fill_p(
        const unsigned int* __restrict__ esort, const int* __restrict__ lstart,
        const int* __restrict__ totals, int* __restrict__ col,
        int* __restrict__ row_ptr, float* __restrict__ dinv,
        const float* __restrict__ x, float* __restrict__ p) {
    __shared__ int hist[256];
    __shared__ int sc[256];
    __shared__ int cur[256];
    __shared__ int segls[256];
    __shared__ int segoff[257];
    __shared__ int bb0;
    int t = threadIdx.x, i = blockIdx.x;     // bucket i

    // 1) global bucket base: scan totals locally
    int tv = (t < NBUCKET) ? totals[t] : 0;
    sc[t] = tv;
    __syncthreads();
    for (int off = 1; off < 256; off <<= 1) {
        int u = (t >= off) ? sc[t - off] : 0;
        __syncthreads();
        sc[t] += u;
        __syncthreads();
    }
    if (t == i) bb0 = sc[t] - tv;
    // 2) segment table for this bucket
    int ls = lstart[i * 256 + t];
    int cnt = lstart[(i + 1) * 256 + t] - ls;
    segls[t] = ls;
    __syncthreads();                          // sc scan done; reuse sc
    sc[t] = cnt;
    __syncthreads();
    for (int off = 1; off < 256; off <<= 1) {
        int u = (t >= off) ? sc[t - off] : 0;
        __syncthreads();
        sc[t] += u;
        __syncthreads();
    }
    segoff[t + 1] = sc[t];
    if (t == 0) segoff[0] = 0;
    hist[t] = 0;
    __syncthreads();
    int base = bb0;
    int total = segoff[256];

    // 3) pass A: fine histogram over (dst&255)
    for (int e = t; e < total; e += 256) {
        int lo = 0, hi = 256;
        while (hi - lo > 1) {
            int mid = (lo + hi) >> 1;
            if (e >= segoff[mid]) lo = mid; else hi = mid;
        }
        unsigned pk = esort[lo * EPB + segls[lo] + (e - segoff[lo])];
        atomicAdd(&hist[(pk >> 16) & 255], 1);
    }
    __syncthreads();
    int v = hist[t];
    sc[t] = v;
    __syncthreads();
    for (int off = 1; off < 256; off <<= 1) {
        int u = (t >= off) ? sc[t - off] : 0;
        __syncthreads();
        sc[t] += u;
        __syncthreads();
    }
    int start = base + sc[t] - v;
    cur[t] = start;
    int node = i * 256 + t;
    float di = rsqrtf((float)(v + 1));  // +1 self-loop
    if (node < N_NODES) {
        row_ptr[node] = start;
        dinv[node] = di;
        float pr[8];
#pragma unroll
        for (int k = 0; k < 6; k++) pr[k] = x[node * 6 + k] * di;
        pr[6] = di;      // multiplies the fused bias row (b_in@W1)
        pr[7] = 0.f;
        *(f32x4*)&p[(size_t)node * 8] = *(f32x4*)&pr[0];
        *(f32x4*)&p[(size_t)node * 8 + 4] = *(f32x4*)&pr[4];
    }
    if (i == 0 && t == 0) row_ptr[N_NODES] = N_EDGES;
    __syncthreads();

    // 4) pass B: scatter col within bucket
    for (int e = t; e < total; e += 256) {
        int lo = 0, hi = 256;
        while (hi - lo > 1) {
            int mid = (lo + hi) >> 1;
            if (e >= segoff[mid]) lo = mid; else hi = mid;
        }
        unsigned pk = esort[lo * EPB + segls[lo] + (e - segoff[lo])];
        int slot = atomicAdd(&cur[(pk >> 16) & 255], 1);
        col[slot] = (int)(pk & 0xffffu);
    }
}

// ---------------- layer 1: L2-resident 8-ch gather + fused 7x128 projection ---------
// t = A@[x*dinv, dinv]; z1 = dinv*(t@Wc) + b1; G = relu(z1)*dinv, stored as fp8 e4m3
// of value 32*G (bit-splice from f16(G/8)), 128 B/node -> layer-2 gather = 1 line/edge.
__global__ __launch_bounds__(256, 8) void k_agg_proj(
        const float* __restrict__ p, const int* __restrict__ row_ptr,
        const int* __restrict__ col, const float* __restrict__ Wcz,
        const float* __restrict__ b1, const float* __restrict__ dinv,
        unsigned char* __restrict__ g1, int n) {
    __shared__ float tl[32][8];
    __shared__ float Wl[8 * 128];
    __shared__ float bl[128];
    int t = threadIdx.x;
    for (int i = t; i < 1024; i += 256) Wl[i] = Wcz[i];
    if (t < 128) bl[t] = b1[t];

    // gather phase: 8 threads/row, 1 fp32 channel each, 4 loads in flight
    int rg = t >> 3, ck = t & 7;
    int row = blockIdx.x * 32 + rg;
    float acc = 0.f;
    if (row < n) {
        acc = p[(size_t)row * 8 + ck];  // self term
        int e = row_ptr[row], e1 = row_ptr[row + 1];
        for (; e + 3 < e1; e += 4) {
            int c0 = col[e], c1 = col[e + 1], c2 = col[e + 2], c3 = col[e + 3];
            float v0 = p[(size_t)c0 * 8 + ck];
            float v1 = p[(size_t)c1 * 8 + ck];
            float v2 = p[(size_t)c2 * 8 + ck];
            float v3 = p[(size_t)c3 * 8 + ck];
            acc += (v0 + v1) + (v2 + v3);
        }
        for (; e < e1; e++) acc += p[(size_t)col[e] * 8 + ck];
    }
    tl[rg][ck] = acc;
    __syncthreads();

    // projection phase: thread -> (row, 16-ch slice); fp8 pack + 16B store
    int rg2 = t >> 3, oc = t & 7;
    int row2 = blockIdx.x * 32 + rg2;
    if (row2 < n) {
        float tr[7];
#pragma unroll
        for (int k = 0; k < 7; k++) tr[k] = tl[rg2][k];
        float di = dinv[row2];
        unsigned w[4] = {0u, 0u, 0u, 0u};
#pragma unroll
        for (int c = 0; c < 16; c++) {
            int ch = oc * 16 + c;
            float z = 0.f;
#pragma unroll
            for (int k = 0; k < 7; k++) z += tr[k] * Wl[k * 128 + ch];
            z = di * z + bl[ch];
            float h = fmaxf(z, 0.f) * di;           // G
            union { _Float16 f; unsigned short u; } cv;
            cv.f = (_Float16)(h * 0.125f);          // G/8 = (32G)*2^-8
            unsigned hb = cv.u;
            unsigned r = hb & 0x7fffu;
            r = r + 0x3fu + ((r >> 7) & 1u);        // RTN-even at bit 7
            unsigned byte = ((hb >> 8) & 0x80u) | ((r >> 7) & 0x7fu);
            w[c >> 2] |= byte << ((c & 3) * 8);
        }
        *(uint4*)&g1[(size_t)row2 * 128 + oc * 16] = make_uint4(w[0], w[1], w[2], w[3]);
    }
}

// ---------------- layer 2: fp8 gather (1 line/edge) + MFMA + fused pooling ----------
__global__ __launch_bounds__(256, 8) void k_gnn2f8(
        const unsigned char* __restrict__ g, const int* __restrict__ row_ptr,
        const int* __restrict__ col, const _Float16* __restrict__ Wt2,
        const float* __restrict__ b2, const float* __restrict__ dinv,
        const int* __restrict__ batch, float* __restrict__ psum,
        float* __restrict__ pmax, int n) {
    constexpr int ROWS = 16, KP = 136;
    __shared__ __align__(16) char smem[ROWS * 128 * 4];   // Hs 8KB > Sl 4.25KB
    _Float16* Sl = (_Float16*)smem;
    float* Hs = (float*)smem;          // aliases Sl; used only after Sl is dead
    int t = threadIdx.x;

    // gather phase: 16 threads/row x 8 fp8 ch; row = 128 B = ONE line-request/edge
    {
        int rl = t >> 4, ck = t & 15;
        int row = blockIdx.x * ROWS + rl;
        f16x8 accA = {};
        f16x8 accB = {};
        const uint2* gb = (const uint2*)g;
        if (row < n) {
            accA = dec8(gb[(size_t)row * 16 + ck]);   // self term
            int e = row_ptr[row], e1 = row_ptr[row + 1];
            for (; e + 3 < e1; e += 4) {
                int c0 = col[e], c1 = col[e + 1], c2 = col[e + 2], c3 = col[e + 3];
                uint2 v0 = gb[(size_t)c0 * 16 + ck];
                uint2 v1 = gb[(size_t)c1 * 16 + ck];
                uint2 v2 = gb[(size_t)c2 * 16 + ck];
                uint2 v3 = gb[(size_t)c3 * 16 + ck];
                accA += dec8(v0);
                accB += dec8(v1);
                accA += dec8(v2);
                accB += dec8(v3);
            }
            if (e + 1 < e1) {
                uint2 v0 = gb[(size_t)col[e] * 16 + ck];
                uint2 v1 = gb[(size_t)col[e + 1] * 16 + ck];
                accA += dec8(v0);
                accB += dec8(v1);
                e += 2;
            }
            if (e < e1) accA += dec8(gb[(size_t)col[e] * 16 + ck]);
        }
        f16x8 o = accA + accB;
        *(f16x8*)&Sl[rl * KP + ck * 8] = o;
    }
    __syncthreads();

    // MFMA phase (K=128): wave -> cols wave*32..+32 (2 tiles)
    int wave = t >> 6;
    int lane = t & 63;
    int m = lane & 15;
    int quad = lane >> 4;
    int col_base = wave * 32;

    f32x4 acc[2] = {};
#pragma unroll
    for (int k0 = 0; k0 < 128; k0 += 32) {
        f16x8 a = *(const f16x8*)&Sl[m * KP + k0 + quad * 8];
#pragma unroll
        for (int ct = 0; ct < 2; ct++) {
            f16x8 bw = *(const f16x8*)(Wt2 + (size_t)(col_base + ct * 16 + m) * 128
                                       + k0 + quad * 8);
            acc[ct] = __builtin_amdgcn_mfma_f32_16x16x32_f16(a, bw, acc[ct], 0, 0, 0);
        }
    }

    // epilogue: h2 -> Hs, pool by sorted batch
    __syncthreads();  // all Sl reads complete before overwriting smem
#pragma unroll
    for (int r = 0; r < 4; r++) {
        int rl = quad * 4 + r;
        int row = blockIdx.x * ROWS + rl;
        float di = (row < n) ? dinv[row] : 0.f;
#pragma unroll
        for (int ct = 0; ct < 2; ct++) {
            int colb = col_base + ct * 16 + m;
            float v = fmaxf(di * acc[ct][r] + b2[colb], 0.f);
            Hs[rl * 128 + colb] = (row < n) ? v : 0.f;
        }
    }
    __syncthreads();
    if (t < 128) {
        int colb = t;
        int row0b = blockIdx.x * ROWS;
        float s = 0.f, mx = 0.f;
        int gcur = batch[row0b < n ? row0b : (n - 1)];
        for (int rr = 0; rr < ROWS; rr++) {
            int row = row0b + rr;
            if (row >= n) break;
            int gi = batch[row];
            if (gi != gcur) {
                atomicAdd(&psum[gcur * 128 + colb], s);
                atomicMax((int*)&pmax[gcur * 128 + colb], __float_as_int(mx));
                s = 0.f; mx = 0.f; gcur = gi;
            }
            float v = Hs[rr * 128 + colb];
            s += v;
            mx = fmaxf(mx, v);
        }
        atomicAdd(&psum[gcur * 128 + colb], s);
        atomicMax((int*)&pmax[gcur * 128 + colb], __float_as_int(mx));
    }
}

// ---------------- final ----------------

__global__ void k_final(const float* __restrict__ psum, const float* __restrict__ pmax,
                        const float* __restrict__ pcnt, const float* __restrict__ Wp,
                        const float* __restrict__ bp, float* __restrict__ out) {
    int t = blockIdx.x * blockDim.x + threadIdx.x;
    if (t >= N_GRAPHS * 256) return;
    int g = t >> 8, j = t & 255;
    float inv = 1.0f / fmaxf(pcnt[g], 1.0f);
    float acc = bp[j];
#pragma unroll 4
    for (int k = 0; k < 128; k++) acc += (psum[g * 128 + k] * inv) * Wp[k * 256 + j];
#pragma unroll 4
    for (int k = 0; k < 128; k++) acc += pmax[g * 128 + k] * Wp[(128 + k) * 256 + j];
    out[t] = fmaxf(acc, 0.f);
}

extern "C" void kernel_launch(void* const* d_in, const int* in_sizes, int n_in,
                              void* d_out, int out_size, void* d_ws, size_t ws_size,
                              hipStream_t stream) {
    const int N = N_NODES, E = N_EDGES;
    const float* x    = (const float*)d_in[0];
    const int*   ei   = (const int*)d_in[1];
    const int*   src  = ei;
    const int*   dst  = ei + E;
    const int*   batch= (const int*)d_in[2];
    const float* W_in = (const float*)d_in[3];
    const float* b_in = (const float*)d_in[4];
    const float* W1   = (const float*)d_in[5];
    const float* b1   = (const float*)d_in[6];
    const float* W2   = (const float*)d_in[7];
    const float* b2   = (const float*)d_in[8];
    const float* Wp   = (const float*)d_in[9];
    const float* bp   = (const float*)d_in[10];
    float* out = (float*)d_out;

    char* p8 = (char*)d_ws;
    int* totals      = (int*)p8;   p8 += 256 * 4;
    int* lstart      = (int*)p8;   p8 += 197 * 256 * 4;       // per-(bucket,chunk) starts
    int* row_ptr     = (int*)p8;   p8 += (N_PAD + 64) * 4;
    int* col         = (int*)p8;   p8 += (size_t)N_EDGES * 4;
    unsigned* esort  = (unsigned*)p8; p8 += (size_t)N_EDGES * 4;
    float* dinv      = (float*)p8; p8 += N_PAD * 4;
    float* Wcz       = (float*)p8; p8 += 1024 * 4;            // fused [W_in;b_in]@W1
    _Float16* Wt2    = (_Float16*)p8; p8 += 128 * 128 * 2;    // 8*W2^T fp16
    float* pfeat     = (float*)p8; p8 += (size_t)N_PAD * 8 * 4; // dinv*[x,1] fp32
    unsigned char* g1f8 = (unsigned char*)p8; p8 += (size_t)N_PAD * 128; // fp8 g1
    float* psum      = (float*)p8; p8 += N_GRAPHS * 128 * 4;
    float* pmax      = (float*)p8; p8 += N_GRAPHS * 128 * 4;
    float* pcnt      = (float*)p8;

    const int TB = 256;
    dim3 blk(TB);

    // prep: Wt2(x8) + Wcz + pcnt + zeros
    k_prep<<<(128 * 128 + 1024 + TB - 1) / TB, blk, 0, stream>>>(
        W_in, b_in, W1, W2, Wt2, Wcz, psum, pmax, totals, batch, pcnt);

    // CSR build: LDS-local bucket sort (coalesced esort) -> segmented fine fill
    k_lsort<<<CB, blk, 0, stream>>>(src, dst, totals, esort, lstart);
    k_fine_fill_p<<<NBUCKET, blk, 0, stream>>>(esort, lstart, totals, col, row_ptr,
                                               dinv, x, pfeat);

    // layer 1: 8-ch fp32 gather (L2-resident) + fused projection -> g1 fp8 (128 B/row)
    k_agg_proj<<<(N + 31) / 32, blk, 0, stream>>>(pfeat, row_ptr, col, Wcz, b1, dinv,
                                                  g1f8, N);

    // layer 2: fp8 gather (1 line/edge) + MFMA + fused pooling
    k_gnn2f8<<<(N + 15) / 16, blk, 0, stream>>>(
        g1f8, row_ptr, col, Wt2, b2, dinv, batch, psum, pmax, N);

    // final MLP
    k_final<<<(N_GRAPHS * 256 + TB - 1) / TB, blk, 0, stream>>>(psum, pmax, pcnt, Wp, bp, out);
}

// Round 10
// 186.007 us; speedup vs baseline: 1.0864x; 1.0864x over previous
//
#include <hip/hip_runtime.h>
#include <hip/hip_fp16.h>

#define N_NODES 50000
#define N_EDGES 800000
#define N_GRAPHS 64
#define N_PAD 50048

#define CB 256                              // coarse-pass blocks
#define EPB (N_EDGES / CB)                  // 3125 edges per block (exact)
#define NBUCKET ((N_NODES + 255) / 256)     // 196 coarse buckets (dst>>8)

typedef _Float16 f16x8 __attribute__((ext_vector_type(8)));
typedef float f32x4 __attribute__((ext_vector_type(4)));
typedef float f32x2 __attribute__((ext_vector_type(2)));

// ---------------- prep: Wt2/32 ->fp16, Wcz = [W_in;b_in]@W1 fp32, pcnt, zeros --------

__global__ void k_prep(const float* __restrict__ W_in, const float* __restrict__ b_in,
                       const float* __restrict__ W1, const float* __restrict__ W2,
                       _Float16* __restrict__ Wt2, float* __restrict__ Wcz,
                       float* psum, float* pmax, int* totals, int* gcursor,
                       const int* __restrict__ batch, float* __restrict__ pcnt) {
    int idx = blockIdx.x * blockDim.x + threadIdx.x;
    if (idx < 128 * 128) {                   // Wt2[n*128+k] = W2[k*128+n]/32
        int n = idx >> 7, k = idx & 127;     // (1/32 compensates fp8 stored value = 32G)
        Wt2[idx] = (_Float16)(W2[k * 128 + n] * 0.03125f);
    } else if (idx < 128 * 128 + 1024) {     // Wcz[k*128+ch], k<6: W_in@W1, k=6: b_in@W1
        int j = idx - 128 * 128;
        int ch = j >> 3, k = j & 7;
        float acc = 0.f;
        if (k < 6) {
            for (int q = 0; q < 64; q++) acc += W_in[k * 64 + q] * W1[q * 128 + ch];
        } else if (k == 6) {
            for (int q = 0; q < 64; q++) acc += b_in[q] * W1[q * 128 + ch];
        }
        Wcz[k * 128 + ch] = acc;
    }
    if (idx < N_GRAPHS * 128) { psum[idx] = 0.f; pmax[idx] = 0.f; }
    if (idx < 256) { totals[idx] = 0; gcursor[idx] = 0; }
    // pcnt via lower_bound on sorted batch (block 0 only)
    if (blockIdx.x == 0) {
        __shared__ int shp[N_GRAPHS + 1];
        int tt = threadIdx.x;
        if (tt <= N_GRAPHS) {
            int lo = 0, hi = N_NODES;
            while (lo < hi) {
                int mid = (lo + hi) >> 1;
                if (batch[mid] < tt) lo = mid + 1; else hi = mid;
            }
            shp[tt] = lo;
        }
        __syncthreads();
        if (tt < N_GRAPHS) pcnt[tt] = (float)(shp[tt + 1] - shp[tt]);
    }
}

// ---------------- CSR build (round-8 proven form) ----------------

__global__ __launch_bounds__(256) void k_coarse_hist(const int* __restrict__ dst,
                                                     int* __restrict__ totals) {
    __shared__ int hist[NBUCKET];
    int t = threadIdx.x, b = blockIdx.x;
    for (int i = t; i < NBUCKET; i += 256) hist[i] = 0;
    __syncthreads();
    int e0 = b * EPB;
    for (int e = e0 + t; e < e0 + EPB; e += 256)
        atomicAdd(&hist[dst[e] >> 8], 1);
    __syncthreads();
    for (int i = t; i < NBUCKET; i += 256)
        if (hist[i] > 0) atomicAdd(&totals[i], hist[i]);
}

// scan(totals) done redundantly per block; gcursor is a zero-based per-bucket
// running offset; slot = local scan base + reserved offset.
__global__ __launch_bounds__(256) void k_scan_scatter(
        const int* __restrict__ src, const int* __restrict__ dst,
        const int* __restrict__ totals, int* __restrict__ bucket_base,
        int* __restrict__ gcursor, unsigned int* __restrict__ esort) {
    __shared__ int cur[256];
    __shared__ int sc[256];
    int t = threadIdx.x, b = blockIdx.x;
    cur[t] = 0;
    __syncthreads();
    int e0 = b * EPB;
    for (int e = e0 + t; e < e0 + EPB; e += 256)
        atomicAdd(&cur[dst[e] >> 8], 1);
    __syncthreads();
    int lcnt = cur[t];
    int v = (t < NBUCKET) ? totals[t] : 0;
    sc[t] = v;
    __syncthreads();
    for (int off = 1; off < 256; off <<= 1) {
        int u = (t >= off) ? sc[t - off] : 0;
        __syncthreads();
        sc[t] += u;
        __syncthreads();
    }
    int base = sc[t] - v;
    int off = (t < NBUCKET && lcnt > 0) ? atomicAdd(&gcursor[t], lcnt) : 0;
    cur[t] = base + off;
    if (b == 0) {
        if (t < NBUCKET) bucket_base[t] = base;
        if (t == 0) bucket_base[NBUCKET] = N_EDGES;
    }
    __syncthreads();
    for (int e = e0 + t; e < e0 + EPB; e += 256) {
        int d = dst[e];
        int slot = atomicAdd(&cur[d >> 8], 1);
        esort[slot] = ((unsigned)(d & 255) << 16) | (unsigned)src[e];  // src < 2^16
    }
}

// fine hist -> row_ptr/dinv, cursor fill of col; store p[node] = dinv*[x0..x5, 1, 0]
__global__ __launch_bounds__(256) void k_fine_fill_p(
        const unsigned int* __restrict__ esort, const int* __restrict__ bucket_base,
        int* __restrict__ col, int* __restrict__ row_ptr, float* __restrict__ dinv,
        const float* __restrict__ x, float* __restrict__ p) {
    __shared__ int hist[256];
    __shared__ int sc[256];
    __shared__ int cur[256];
    int t = threadIdx.x, b = blockIdx.x;
    hist[t] = 0;
    __syncthreads();
    int base = bucket_base[b], end = bucket_base[b + 1];
    for (int e = base + t; e < end; e += 256)
        atomicAdd(&hist[(esort[e] >> 16) & 255], 1);
    __syncthreads();
    int v = hist[t];
    sc[t] = v;
    __syncthreads();
    for (int off = 1; off < 256; off <<= 1) {
        int u = (t >= off) ? sc[t - off] : 0;
        __syncthreads();
        sc[t] += u;
        __syncthreads();
    }
    int start = base + sc[t] - v;
    cur[t] = start;
    int node = b * 256 + t;
    float di = rsqrtf((float)(v + 1));  // +1 self-loop
    if (node < N_NODES) {
        row_ptr[node] = start;
        dinv[node] = di;
        float pr[8];
#pragma unroll
        for (int k = 0; k < 6; k++) pr[k] = x[node * 6 + k] * di;
        pr[6] = di;      // multiplies the fused bias row (b_in@W1)
        pr[7] = 0.f;
        *(f32x4*)&p[(size_t)node * 8] = *(f32x4*)&pr[0];
        *(f32x4*)&p[(size_t)node * 8 + 4] = *(f32x4*)&pr[4];
    }
    if (b == 0 && t == 0) row_ptr[N_NODES] = N_EDGES;
    __syncthreads();
    for (int e = base + t; e < end; e += 256) {
        unsigned pk = esort[e];
        int slot = atomicAdd(&cur[(pk >> 16) & 255], 1);
        col[slot] = (int)(pk & 0xffffu);
    }
}

// ---------------- layer 1: L2-resident 8-ch gather + fused 7x128 projection ---------
// t = A@[x*dinv, dinv]; z1 = dinv*(t@Wc) + b1; G = relu(z1)*dinv, stored as e4m3
// fp8 of 32*G via HW v_cvt_pk_fp8_f32; 128 B/node -> layer-2 gather = 1 line/edge.
__global__ __launch_bounds__(256, 8) void k_agg_proj(
        const float* __restrict__ p, const int* __restrict__ row_ptr,
        const int* __restrict__ col, const float* __restrict__ Wcz,
        const float* __restrict__ b1, const float* __restrict__ dinv,
        unsigned char* __restrict__ g1, int n) {
    __shared__ float tl[32][8];
    __shared__ float Wl[8 * 128];
    __shared__ float bl[128];
    int t = threadIdx.x;
    for (int i = t; i < 1024; i += 256) Wl[i] = Wcz[i];
    if (t < 128) bl[t] = b1[t];

    // gather phase: 8 threads/row, 1 fp32 channel each, 4 loads in flight
    int rg = t >> 3, ck = t & 7;
    int row = blockIdx.x * 32 + rg;
    float acc = 0.f;
    if (row < n) {
        acc = p[(size_t)row * 8 + ck];  // self term
        int e = row_ptr[row], e1 = row_ptr[row + 1];
        for (; e + 3 < e1; e += 4) {
            int c0 = col[e], c1 = col[e + 1], c2 = col[e + 2], c3 = col[e + 3];
            float v0 = p[(size_t)c0 * 8 + ck];
            float v1 = p[(size_t)c1 * 8 + ck];
            float v2 = p[(size_t)c2 * 8 + ck];
            float v3 = p[(size_t)c3 * 8 + ck];
            acc += (v0 + v1) + (v2 + v3);
        }
        for (; e < e1; e++) acc += p[(size_t)col[e] * 8 + ck];
    }
    tl[rg][ck] = acc;
    __syncthreads();

    // projection phase: thread -> (row, 16-ch slice); HW fp8 pack + 16B store
    int rg2 = t >> 3, oc = t & 7;
    int row2 = blockIdx.x * 32 + rg2;
    if (row2 < n) {
        float tr[7];
#pragma unroll
        for (int k = 0; k < 7; k++) tr[k] = tl[rg2][k];
        float di = dinv[row2];
        float hv[16];
#pragma unroll
        for (int c = 0; c < 16; c++) {
            int ch = oc * 16 + c;
            float z = 0.f;
#pragma unroll
            for (int k = 0; k < 7; k++) z += tr[k] * Wl[k * 128 + ch];
            z = di * z + bl[ch];
            hv[c] = fmaxf(z, 0.f) * di * 32.f;      // 32*G  (<= ~160 < 448)
        }
        unsigned w[4];
#pragma unroll
        for (int q = 0; q < 4; q++) {
            int word = 0;
            word = __builtin_amdgcn_cvt_pk_fp8_f32(hv[q * 4 + 0], hv[q * 4 + 1], word, false);
            word = __builtin_amdgcn_cvt_pk_fp8_f32(hv[q * 4 + 2], hv[q * 4 + 3], word, true);
            w[q] = (unsigned)word;
        }
        *(uint4*)&g1[(size_t)row2 * 128 + oc * 16] = make_uint4(w[0], w[1], w[2], w[3]);
    }
}

// ---------------- layer 2: fp8 gather (1 line/edge, HW decode) + MFMA + pooling -----
__global__ __launch_bounds__(256, 8) void k_gnn2f8(
        const unsigned char* __restrict__ g, const int* __restrict__ row_ptr,
        const int* __restrict__ col, const _Float16* __restrict__ Wt2,
        const float* __restrict__ b2, const float* __restrict__ dinv,
        const int* __restrict__ batch, float* __restrict__ psum,
        float* __restrict__ pmax, int n) {
    constexpr int ROWS = 16, KP = 136;
    __shared__ __align__(16) char smem[ROWS * 128 * 4];   // Hs 8KB > Sl 4.25KB
    _Float16* Sl = (_Float16*)smem;
    float* Hs = (float*)smem;          // aliases Sl; used only after Sl is dead
    int t = threadIdx.x;

    // gather phase: 16 threads/row x 8 fp8 ch; row = 128 B = ONE line-request/edge.
    // HW decode: v_cvt_pk_f32_fp8 (1 inst / 2 ch) + v_pk_add_f32 accumulate.
    {
        int rl = t >> 4, ck = t & 15;
        int row = blockIdx.x * ROWS + rl;
        f32x2 aA[4] = {};
        f32x2 aB[4] = {};
        const uint2* gb = (const uint2*)g;
        auto addv = [](f32x2* acc, uint2 w) {
            acc[0] += __builtin_amdgcn_cvt_pk_f32_fp8((int)w.x, false);
            acc[1] += __builtin_amdgcn_cvt_pk_f32_fp8((int)w.x, true);
            acc[2] += __builtin_amdgcn_cvt_pk_f32_fp8((int)w.y, false);
            acc[3] += __builtin_amdgcn_cvt_pk_f32_fp8((int)w.y, true);
        };
        if (row < n) {
            addv(aA, gb[(size_t)row * 16 + ck]);      // self term
            int e = row_ptr[row], e1 = row_ptr[row + 1];
            for (; e + 3 < e1; e += 4) {
                int c0 = col[e], c1 = col[e + 1], c2 = col[e + 2], c3 = col[e + 3];
                uint2 v0 = gb[(size_t)c0 * 16 + ck];
                uint2 v1 = gb[(size_t)c1 * 16 + ck];
                uint2 v2 = gb[(size_t)c2 * 16 + ck];
                uint2 v3 = gb[(size_t)c3 * 16 + ck];
                addv(aA, v0);
                addv(aB, v1);
                addv(aA, v2);
                addv(aB, v3);
            }
            if (e + 1 < e1) {
                uint2 v0 = gb[(size_t)col[e] * 16 + ck];
                uint2 v1 = gb[(size_t)col[e + 1] * 16 + ck];
                addv(aA, v0);
                addv(aB, v1);
                e += 2;
            }
            if (e < e1) addv(aA, gb[(size_t)col[e] * 16 + ck]);
        }
        f16x8 o;
#pragma unroll
        for (int j = 0; j < 4; j++) {
            o[2 * j] = (_Float16)(aA[j].x + aB[j].x);
            o[2 * j + 1] = (_Float16)(aA[j].y + aB[j].y);
        }
        *(f16x8*)&Sl[rl * KP + ck * 8] = o;
    }
    __syncthreads();

    // MFMA phase (K=128): wave -> cols wave*32..+32 (2 tiles)
    int wave = t >> 6;
    int lane = t & 63;
    int m = lane & 15;
    int quad = lane >> 4;
    int col_base = wave * 32;

    f32x4 acc[2] = {};
#pragma unroll
    for (int k0 = 0; k0 < 128; k0 += 32) {
        f16x8 a = *(const f16x8*)&Sl[m * KP + k0 + quad * 8];
#pragma unroll
        for (int ct = 0; ct < 2; ct++) {
            f16x8 bw = *(const f16x8*)(Wt2 + (size_t)(col_base + ct * 16 + m) * 128
                                       + k0 + quad * 8);
            acc[ct] = __builtin_amdgcn_mfma_f32_16x16x32_f16(a, bw, acc[ct], 0, 0, 0);
        }
    }

    // epilogue: h2 -> Hs, pool by sorted batch
    __syncthreads();  // all Sl reads complete before overwriting smem
#pragma unroll
    for (int r = 0; r < 4; r++) {
        int rl = quad * 4 + r;
        int row = blockIdx.x * ROWS + rl;
        float di = (row < n) ? dinv[row] : 0.f;
#pragma unroll
        for (int ct = 0; ct < 2; ct++) {
            int colb = col_base + ct * 16 + m;
            float v = fmaxf(di * acc[ct][r] + b2[colb], 0.f);
            Hs[rl * 128 + colb] = (row < n) ? v : 0.f;
        }
    }
    __syncthreads();
    if (t < 128) {
        int colb = t;
        int row0b = blockIdx.x * ROWS;
        float s = 0.f, mx = 0.f;
        int gcur = batch[row0b < n ? row0b : (n - 1)];
        for (int rr = 0; rr < ROWS; rr++) {
            int row = row0b + rr;
            if (row >= n) break;
            int gi = batch[row];
            if (gi != gcur) {
                atomicAdd(&psum[gcur * 128 + colb], s);
                atomicMax((int*)&pmax[gcur * 128 + colb], __float_as_int(mx));
                s = 0.f; mx = 0.f; gcur = gi;
            }
            float v = Hs[rr * 128 + colb];
            s += v;
            mx = fmaxf(mx, v);
        }
        atomicAdd(&psum[gcur * 128 + colb], s);
        atomicMax((int*)&pmax[gcur * 128 + colb], __float_as_int(mx));
    }
}

// ---------------- final ----------------

__global__ void k_final(const float* __restrict__ psum, const float* __restrict__ pmax,
                        const float* __restrict__ pcnt, const float* __restrict__ Wp,
                        const float* __restrict__ bp, float* __restrict__ out) {
    int t = blockIdx.x * blockDim.x + threadIdx.x;
    if (t >= N_GRAPHS * 256) return;
    int g = t >> 8, j = t & 255;
    float inv = 1.0f / fmaxf(pcnt[g], 1.0f);
    float acc = bp[j];
#pragma unroll 4
    for (int k = 0; k < 128; k++) acc += (psum[g * 128 + k] * inv) * Wp[k * 256 + j];
#pragma unroll 4
    for (int k = 0; k < 128; k++) acc += pmax[g * 128 + k] * Wp[(128 + k) * 256 + j];
    out[t] = fmaxf(acc, 0.f);
}

extern "C" void kernel_launch(void* const* d_in, const int* in_sizes, int n_in,
                              void* d_out, int out_size, void* d_ws, size_t ws_size,
                              hipStream_t stream) {
    const int N = N_NODES, E = N_EDGES;
    const float* x    = (const float*)d_in[0];
    const int*   ei   = (const int*)d_in[1];
    const int*   src  = ei;
    const int*   dst  = ei + E;
    const int*   batch= (const int*)d_in[2];
    const float* W_in = (const float*)d_in[3];
    const float* b_in = (const float*)d_in[4];
    const float* W1   = (const float*)d_in[5];
    const float* b1   = (const float*)d_in[6];
    const float* W2   = (const float*)d_in[7];
    const float* b2   = (const float*)d_in[8];
    const float* Wp   = (const float*)d_in[9];
    const float* bp   = (const float*)d_in[10];
    float* out = (float*)d_out;

    char* p8 = (char*)d_ws;
    int* totals      = (int*)p8;   p8 += 256 * 4;
    int* bucket_base = (int*)p8;   p8 += 256 * 4;
    int* gcursor     = (int*)p8;   p8 += 256 * 4;
    int* row_ptr     = (int*)p8;   p8 += (N_PAD + 64) * 4;
    int* col         = (int*)p8;   p8 += (size_t)N_EDGES * 4;
    unsigned* esort  = (unsigned*)p8; p8 += (size_t)N_EDGES * 4;
    float* dinv      = (float*)p8; p8 += N_PAD * 4;
    float* Wcz       = (float*)p8; p8 += 1024 * 4;            // fused [W_in;b_in]@W1
    _Float16* Wt2    = (_Float16*)p8; p8 += 128 * 128 * 2;    // W2^T/32 fp16
    float* pfeat     = (float*)p8; p8 += (size_t)N_PAD * 8 * 4; // dinv*[x,1] fp32
    unsigned char* g1f8 = (unsigned char*)p8; p8 += (size_t)N_PAD * 128; // fp8 g1 (32G)
    float* psum      = (float*)p8; p8 += N_GRAPHS * 128 * 4;
    float* pmax      = (float*)p8; p8 += N_GRAPHS * 128 * 4;
    float* pcnt      = (float*)p8;

    const int TB = 256;
    dim3 blk(TB);

    // prep: Wt2(/32) + Wcz + pcnt + zeros
    k_prep<<<(128 * 128 + 1024 + TB - 1) / TB, blk, 0, stream>>>(
        W_in, b_in, W1, W2, Wt2, Wcz, psum, pmax, totals, gcursor, batch, pcnt);

    // CSR build (round-8 proven: hist + merged scan-scatter)
    k_coarse_hist<<<CB, blk, 0, stream>>>(dst, totals);
    k_scan_scatter<<<CB, blk, 0, stream>>>(src, dst, totals, bucket_base, gcursor, esort);
    k_fine_fill_p<<<NBUCKET, blk, 0, stream>>>(esort, bucket_base, col, row_ptr, dinv,
                                               x, pfeat);

    // layer 1: 8-ch fp32 gather (L2-resident) + fused projection -> g1 fp8 (128 B/row)
    k_agg_proj<<<(N + 31) / 32, blk, 0, stream>>>(pfeat, row_ptr, col, Wcz, b1, dinv,
                                                  g1f8, N);

    // layer 2: fp8 gather (1 line/edge, HW decode) + MFMA + fused pooling
    k_gnn2f8<<<(N + 15) / 16, blk, 0, stream>>>(
        g1f8, row_ptr, col, Wt2, b2, dinv, batch, psum, pmax, N);

    // final MLP
    k_final<<<(N_GRAPHS * 256 + TB - 1) / TB, blk, 0, stream>>>(psum, pmax, pcnt, Wp, bp, out);
}

// Round 11
// 177.670 us; speedup vs baseline: 1.1374x; 1.0469x over previous
//
#include <hip/hip_runtime.h>
#include <hip/hip_fp16.h>

#define N_NODES 50000
#define N_EDGES 800000
#define N_GRAPHS 64
#define N_PAD 50048

#define CB 256                              // scatter blocks (= edge chunks)
#define EPB (N_EDGES / CB)                  // 3125 edges per block (exact)
#define NBUCKET ((N_NODES + 255) / 256)     // 196 coarse buckets (dst>>8)
#define BCAP 5120                           // fixed bucket capacity (mean 4096 + 16 sigma)

typedef _Float16 f16x8 __attribute__((ext_vector_type(8)));
typedef float f32x4 __attribute__((ext_vector_type(4)));
typedef float f32x2 __attribute__((ext_vector_type(2)));

// ---------------- prep: Wt2/32 ->fp16, Wcz = [W_in;b_in]@W1 fp32, pcnt, zeros --------

__global__ void k_prep(const float* __restrict__ W_in, const float* __restrict__ b_in,
                       const float* __restrict__ W1, const float* __restrict__ W2,
                       _Float16* __restrict__ Wt2, float* __restrict__ Wcz,
                       float* psum, float* pmax, int* gcursor,
                       const int* __restrict__ batch, float* __restrict__ pcnt) {
    int idx = blockIdx.x * blockDim.x + threadIdx.x;
    if (idx < 128 * 128) {                   // Wt2[n*128+k] = W2[k*128+n]/32
        int n = idx >> 7, k = idx & 127;     // (1/32 compensates fp8 stored value = 32G)
        Wt2[idx] = (_Float16)(W2[k * 128 + n] * 0.03125f);
    } else if (idx < 128 * 128 + 1024) {     // Wcz[k*128+ch], k<6: W_in@W1, k=6: b_in@W1
        int j = idx - 128 * 128;
        int ch = j >> 3, k = j & 7;
        float acc = 0.f;
        if (k < 6) {
            for (int q = 0; q < 64; q++) acc += W_in[k * 64 + q] * W1[q * 128 + ch];
        } else if (k == 6) {
            for (int q = 0; q < 64; q++) acc += b_in[q] * W1[q * 128 + ch];
        }
        Wcz[k * 128 + ch] = acc;
    }
    if (idx < N_GRAPHS * 128) { psum[idx] = 0.f; pmax[idx] = 0.f; }
    if (idx < 256) gcursor[idx] = 0;
    // pcnt via lower_bound on sorted batch (block 0 only)
    if (blockIdx.x == 0) {
        __shared__ int shp[N_GRAPHS + 1];
        int tt = threadIdx.x;
        if (tt <= N_GRAPHS) {
            int lo = 0, hi = N_NODES;
            while (lo < hi) {
                int mid = (lo + hi) >> 1;
                if (batch[mid] < tt) lo = mid + 1; else hi = mid;
            }
            shp[tt] = lo;
        }
        __syncthreads();
        if (tt < N_GRAPHS) pcnt[tt] = (float)(shp[tt + 1] - shp[tt]);
    }
}

// ---------------- CSR build: direct scatter into fixed-capacity bucket regions ------
// No totals pre-pass: block hist -> per-bucket range reservation via gcursor ->
// scatter packed ((dst&255)<<16 | src) into esort[bucket*BCAP + offset].
__global__ __launch_bounds__(256) void k_scan_scatter(
        const int* __restrict__ src, const int* __restrict__ dst,
        int* __restrict__ gcursor, unsigned int* __restrict__ esort) {
    __shared__ int cur[256];
    int t = threadIdx.x, b = blockIdx.x;
    cur[t] = 0;
    __syncthreads();
    int e0 = b * EPB;
    for (int e = e0 + t; e < e0 + EPB; e += 256)
        atomicAdd(&cur[dst[e] >> 8], 1);
    __syncthreads();
    int lcnt = cur[t];
    int off = (t < NBUCKET && lcnt > 0) ? atomicAdd(&gcursor[t], lcnt) : 0;
    cur[t] = t * BCAP + off;
    __syncthreads();
    for (int e = e0 + t; e < e0 + EPB; e += 256) {
        int d = dst[e];
        int slot = atomicAdd(&cur[d >> 8], 1);
        esort[slot] = ((unsigned)(d & 255) << 16) | (unsigned)src[e];  // src < 2^16
    }
}

// one block per bucket: local scan of gcursor -> global base; fine hist ->
// row_ptr/dinv/pfeat; cursor fill of col (from the bucket's fixed region).
__global__ __launch_bounds__(256) void k_fine_fill_p(
        const unsigned int* __restrict__ esort, const int* __restrict__ gcursor,
        int* __restrict__ col, int* __restrict__ row_ptr, float* __restrict__ dinv,
        const float* __restrict__ x, float* __restrict__ p) {
    __shared__ int hist[256];
    __shared__ int sc[256];
    __shared__ int cur[256];
    __shared__ int bb[2];                    // [0]=global base, [1]=count
    int t = threadIdx.x, b = blockIdx.x;
    // 1) bucket base = exclusive prefix of gcursor counts
    int tv = (t < NBUCKET) ? gcursor[t] : 0;
    sc[t] = tv;
    __syncthreads();
    for (int off = 1; off < 256; off <<= 1) {
        int u = (t >= off) ? sc[t - off] : 0;
        __syncthreads();
        sc[t] += u;
        __syncthreads();
    }
    if (t == b) { bb[0] = sc[t] - tv; bb[1] = tv; }
    hist[t] = 0;
    __syncthreads();
    int base = bb[0];
    size_t sbase = (size_t)b * BCAP;
    int total = bb[1];
    // 2) fine histogram over (dst&255)
    for (int e = t; e < total; e += 256)
        atomicAdd(&hist[(esort[sbase + e] >> 16) & 255], 1);
    __syncthreads();
    int v = hist[t];
    sc[t] = v;
    __syncthreads();
    for (int off = 1; off < 256; off <<= 1) {
        int u = (t >= off) ? sc[t - off] : 0;
        __syncthreads();
        sc[t] += u;
        __syncthreads();
    }
    int start = base + sc[t] - v;
    cur[t] = start;
    int node = b * 256 + t;
    float di = rsqrtf((float)(v + 1));  // +1 self-loop
    if (node < N_NODES) {
        row_ptr[node] = start;
        dinv[node] = di;
        float pr[8];
#pragma unroll
        for (int k = 0; k < 6; k++) pr[k] = x[node * 6 + k] * di;
        pr[6] = di;      // multiplies the fused bias row (b_in@W1)
        pr[7] = 0.f;
        *(f32x4*)&p[(size_t)node * 8] = *(f32x4*)&pr[0];
        *(f32x4*)&p[(size_t)node * 8 + 4] = *(f32x4*)&pr[4];
    }
    if (b == 0 && t == 0) row_ptr[N_NODES] = N_EDGES;
    __syncthreads();
    // 3) scatter col within bucket
    for (int e = t; e < total; e += 256) {
        unsigned pk = esort[sbase + e];
        int slot = atomicAdd(&cur[(pk >> 16) & 255], 1);
        col[slot] = (int)(pk & 0xffffu);
    }
}

// ---------------- layer 1: L2-resident 8-ch gather + fused 7x128 projection ---------
// t = A@[x*dinv, dinv]; z1 = dinv*(t@Wc) + b1; G = relu(z1)*dinv, stored as e4m3
// fp8 of 32*G via HW v_cvt_pk_fp8_f32; 128 B/node -> layer-2 gather = 1 line/edge.
__global__ __launch_bounds__(256, 8) void k_agg_proj(
        const float* __restrict__ p, const int* __restrict__ row_ptr,
        const int* __restrict__ col, const float* __restrict__ Wcz,
        const float* __restrict__ b1, const float* __restrict__ dinv,
        unsigned char* __restrict__ g1, int n) {
    __shared__ float tl[32][8];
    __shared__ float Wl[8 * 128];
    __shared__ float bl[128];
    int t = threadIdx.x;
    for (int i = t; i < 1024; i += 256) Wl[i] = Wcz[i];
    if (t < 128) bl[t] = b1[t];

    // gather phase: 8 threads/row, 1 fp32 channel each, 4 loads in flight
    int rg = t >> 3, ck = t & 7;
    int row = blockIdx.x * 32 + rg;
    float acc = 0.f;
    if (row < n) {
        acc = p[(size_t)row * 8 + ck];  // self term
        int e = row_ptr[row], e1 = row_ptr[row + 1];
        for (; e + 3 < e1; e += 4) {
            int c0 = col[e], c1 = col[e + 1], c2 = col[e + 2], c3 = col[e + 3];
            float v0 = p[(size_t)c0 * 8 + ck];
            float v1 = p[(size_t)c1 * 8 + ck];
            float v2 = p[(size_t)c2 * 8 + ck];
            float v3 = p[(size_t)c3 * 8 + ck];
            acc += (v0 + v1) + (v2 + v3);
        }
        for (; e < e1; e++) acc += p[(size_t)col[e] * 8 + ck];
    }
    tl[rg][ck] = acc;
    __syncthreads();

    // projection phase: thread -> (row, 16-ch slice); HW fp8 pack + 16B store
    int rg2 = t >> 3, oc = t & 7;
    int row2 = blockIdx.x * 32 + rg2;
    if (row2 < n) {
        float tr[7];
#pragma unroll
        for (int k = 0; k < 7; k++) tr[k] = tl[rg2][k];
        float di = dinv[row2];
        float hv[16];
#pragma unroll
        for (int c = 0; c < 16; c++) {
            int ch = oc * 16 + c;
            float z = 0.f;
#pragma unroll
            for (int k = 0; k < 7; k++) z += tr[k] * Wl[k * 128 + ch];
            z = di * z + bl[ch];
            hv[c] = fmaxf(z, 0.f) * di * 32.f;      // 32*G  (<= ~160 < 448)
        }
        unsigned w[4];
#pragma unroll
        for (int q = 0; q < 4; q++) {
            int word = 0;
            word = __builtin_amdgcn_cvt_pk_fp8_f32(hv[q * 4 + 0], hv[q * 4 + 1], word, false);
            word = __builtin_amdgcn_cvt_pk_fp8_f32(hv[q * 4 + 2], hv[q * 4 + 3], word, true);
            w[q] = (unsigned)word;
        }
        *(uint4*)&g1[(size_t)row2 * 128 + oc * 16] = make_uint4(w[0], w[1], w[2], w[3]);
    }
}

// ---------------- layer 2: fp8 gather (1 line/edge, HW decode) + MFMA + pooling -----
__global__ __launch_bounds__(256, 8) void k_gnn2f8(
        const unsigned char* __restrict__ g, const int* __restrict__ row_ptr,
        const int* __restrict__ col, const _Float16* __restrict__ Wt2,
        const float* __restrict__ b2, const float* __restrict__ dinv,
        const int* __restrict__ batch, float* __restrict__ psum,
        float* __restrict__ pmax, int n) {
    constexpr int ROWS = 16, KP = 136;
    __shared__ __align__(16) char smem[ROWS * 128 * 4];   // Hs 8KB > Sl 4.25KB
    _Float16* Sl = (_Float16*)smem;
    float* Hs = (float*)smem;          // aliases Sl; used only after Sl is dead
    int t = threadIdx.x;

    // gather phase: 16 threads/row x 8 fp8 ch; row = 128 B = ONE line-request/edge.
    // HW decode: v_cvt_pk_f32_fp8 (1 inst / 2 ch) + v_pk_add_f32 accumulate.
    {
        int rl = t >> 4, ck = t & 15;
        int row = blockIdx.x * ROWS + rl;
        f32x2 aA[4] = {};
        f32x2 aB[4] = {};
        const uint2* gb = (const uint2*)g;
        auto addv = [](f32x2* acc, uint2 w) {
            acc[0] += __builtin_amdgcn_cvt_pk_f32_fp8((int)w.x, false);
            acc[1] += __builtin_amdgcn_cvt_pk_f32_fp8((int)w.x, true);
            acc[2] += __builtin_amdgcn_cvt_pk_f32_fp8((int)w.y, false);
            acc[3] += __builtin_amdgcn_cvt_pk_f32_fp8((int)w.y, true);
        };
        if (row < n) {
            addv(aA, gb[(size_t)row * 16 + ck]);      // self term
            int e = row_ptr[row], e1 = row_ptr[row + 1];
            for (; e + 3 < e1; e += 4) {
                int c0 = col[e], c1 = col[e + 1], c2 = col[e + 2], c3 = col[e + 3];
                uint2 v0 = gb[(size_t)c0 * 16 + ck];
                uint2 v1 = gb[(size_t)c1 * 16 + ck];
                uint2 v2 = gb[(size_t)c2 * 16 + ck];
                uint2 v3 = gb[(size_t)c3 * 16 + ck];
                addv(aA, v0);
                addv(aB, v1);
                addv(aA, v2);
                addv(aB, v3);
            }
            if (e + 1 < e1) {
                uint2 v0 = gb[(size_t)col[e] * 16 + ck];
                uint2 v1 = gb[(size_t)col[e + 1] * 16 + ck];
                addv(aA, v0);
                addv(aB, v1);
                e += 2;
            }
            if (e < e1) addv(aA, gb[(size_t)col[e] * 16 + ck]);
        }
        f16x8 o;
#pragma unroll
        for (int j = 0; j < 4; j++) {
            o[2 * j] = (_Float16)(aA[j].x + aB[j].x);
            o[2 * j + 1] = (_Float16)(aA[j].y + aB[j].y);
        }
        *(f16x8*)&Sl[rl * KP + ck * 8] = o;
    }
    __syncthreads();

    // MFMA phase (K=128): wave -> cols wave*32..+32 (2 tiles)
    int wave = t >> 6;
    int lane = t & 63;
    int m = lane & 15;
    int quad = lane >> 4;
    int col_base = wave * 32;

    f32x4 acc[2] = {};
#pragma unroll
    for (int k0 = 0; k0 < 128; k0 += 32) {
        f16x8 a = *(const f16x8*)&Sl[m * KP + k0 + quad * 8];
#pragma unroll
        for (int ct = 0; ct < 2; ct++) {
            f16x8 bw = *(const f16x8*)(Wt2 + (size_t)(col_base + ct * 16 + m) * 128
                                       + k0 + quad * 8);
            acc[ct] = __builtin_amdgcn_mfma_f32_16x16x32_f16(a, bw, acc[ct], 0, 0, 0);
        }
    }

    // epilogue: h2 -> Hs, pool by sorted batch
    __syncthreads();  // all Sl reads complete before overwriting smem
#pragma unroll
    for (int r = 0; r < 4; r++) {
        int rl = quad * 4 + r;
        int row = blockIdx.x * ROWS + rl;
        float di = (row < n) ? dinv[row] : 0.f;
#pragma unroll
        for (int ct = 0; ct < 2; ct++) {
            int colb = col_base + ct * 16 + m;
            float v = fmaxf(di * acc[ct][r] + b2[colb], 0.f);
            Hs[rl * 128 + colb] = (row < n) ? v : 0.f;
        }
    }
    __syncthreads();
    if (t < 128) {
        int colb = t;
        int row0b = blockIdx.x * ROWS;
        float s = 0.f, mx = 0.f;
        int gcur = batch[row0b < n ? row0b : (n - 1)];
        for (int rr = 0; rr < ROWS; rr++) {
            int row = row0b + rr;
            if (row >= n) break;
            int gi = batch[row];
            if (gi != gcur) {
                atomicAdd(&psum[gcur * 128 + colb], s);
                atomicMax((int*)&pmax[gcur * 128 + colb], __float_as_int(mx));
                s = 0.f; mx = 0.f; gcur = gi;
            }
            float v = Hs[rr * 128 + colb];
            s += v;
            mx = fmaxf(mx, v);
        }
        atomicAdd(&psum[gcur * 128 + colb], s);
        atomicMax((int*)&pmax[gcur * 128 + colb], __float_as_int(mx));
    }
}

// ---------------- final ----------------

__global__ void k_final(const float* __restrict__ psum, const float* __restrict__ pmax,
                        const float* __restrict__ pcnt, const float* __restrict__ Wp,
                        const float* __restrict__ bp, float* __restrict__ out) {
    int t = blockIdx.x * blockDim.x + threadIdx.x;
    if (t >= N_GRAPHS * 256) return;
    int g = t >> 8, j = t & 255;
    float inv = 1.0f / fmaxf(pcnt[g], 1.0f);
    float acc = bp[j];
#pragma unroll 4
    for (int k = 0; k < 128; k++) acc += (psum[g * 128 + k] * inv) * Wp[k * 256 + j];
#pragma unroll 4
    for (int k = 0; k < 128; k++) acc += pmax[g * 128 + k] * Wp[(128 + k) * 256 + j];
    out[t] = fmaxf(acc, 0.f);
}

extern "C" void kernel_launch(void* const* d_in, const int* in_sizes, int n_in,
                              void* d_out, int out_size, void* d_ws, size_t ws_size,
                              hipStream_t stream) {
    const int N = N_NODES, E = N_EDGES;
    const float* x    = (const float*)d_in[0];
    const int*   ei   = (const int*)d_in[1];
    const int*   src  = ei;
    const int*   dst  = ei + E;
    const int*   batch= (const int*)d_in[2];
    const float* W_in = (const float*)d_in[3];
    const float* b_in = (const float*)d_in[4];
    const float* W1   = (const float*)d_in[5];
    const float* b1   = (const float*)d_in[6];
    const float* W2   = (const float*)d_in[7];
    const float* b2   = (const float*)d_in[8];
    const float* Wp   = (const float*)d_in[9];
    const float* bp   = (const float*)d_in[10];
    float* out = (float*)d_out;

    char* p8 = (char*)d_ws;
    int* gcursor     = (int*)p8;   p8 += 256 * 4;
    int* row_ptr     = (int*)p8;   p8 += (N_PAD + 64) * 4;
    int* col         = (int*)p8;   p8 += (size_t)N_EDGES * 4;
    unsigned* esort  = (unsigned*)p8; p8 += (size_t)NBUCKET * BCAP * 4;  // 4.0 MB
    float* dinv      = (float*)p8; p8 += N_PAD * 4;
    float* Wcz       = (float*)p8; p8 += 1024 * 4;            // fused [W_in;b_in]@W1
    _Float16* Wt2    = (_Float16*)p8; p8 += 128 * 128 * 2;    // W2^T/32 fp16
    float* pfeat     = (float*)p8; p8 += (size_t)N_PAD * 8 * 4; // dinv*[x,1] fp32
    unsigned char* g1f8 = (unsigned char*)p8; p8 += (size_t)N_PAD * 128; // fp8 g1 (32G)
    float* psum      = (float*)p8; p8 += N_GRAPHS * 128 * 4;
    float* pmax      = (float*)p8; p8 += N_GRAPHS * 128 * 4;
    float* pcnt      = (float*)p8;

    const int TB = 256;
    dim3 blk(TB);

    // prep: Wt2(/32) + Wcz + pcnt + zeros
    k_prep<<<(128 * 128 + 1024 + TB - 1) / TB, blk, 0, stream>>>(
        W_in, b_in, W1, W2, Wt2, Wcz, psum, pmax, gcursor, batch, pcnt);

    // CSR build: direct scatter into fixed-capacity regions (no totals pre-pass)
    k_scan_scatter<<<CB, blk, 0, stream>>>(src, dst, gcursor, esort);
    k_fine_fill_p<<<NBUCKET, blk, 0, stream>>>(esort, gcursor, col, row_ptr, dinv,
                                               x, pfeat);

    // layer 1: 8-ch fp32 gather (L2-resident) + fused projection -> g1 fp8 (128 B/row)
    k_agg_proj<<<(N + 31) / 32, blk, 0, stream>>>(pfeat, row_ptr, col, Wcz, b1, dinv,
                                                  g1f8, N);

    // layer 2: fp8 gather (1 line/edge, HW decode) + MFMA + fused pooling
    k_gnn2f8<<<(N + 15) / 16, blk, 0, stream>>>(
        g1f8, row_ptr, col, Wt2, b2, dinv, batch, psum, pmax, N);

    // final MLP
    k_final<<<(N_GRAPHS * 256 + TB - 1) / TB, blk, 0, stream>>>(psum, pmax, pcnt, Wp, bp, out);
}